// Round 2
// 305.213 us; speedup vs baseline: 1.0207x; 1.0207x over previous
//
#include <hip/hip_runtime.h>

#define B_   32
#define C_   64
#define H_   128
#define W_   128
#define HW_  (H_ * W_)       // 16384
#define CHW_ (C_ * HW_)      // 1048576
#define TH_  4               // output rows per block
#define CW_  64              // half-row chunk width

// Fused: box-mean(3x3, edge-clipped) -> 1x1 conv (64x64) -> residual add.
// Block = (batch, 4-row strip), 256 threads = 4 waves. Row processed as two
// 64-px chunks so LDS = 33 KB -> 4 blocks/CU (was 48 KB -> 3).
// Lane (jj = lane&15 -> px f4, m = wid*4 + (lane>>4) in 0..15).
// Filter: lane filters channels c = m+16p (p=0..3); center row saved in regs.
// Matmul: lane accumulates out-channels o = m+16*oi -- SAME channel set it
// filtered, so the residual x comes from the saved registers (no re-read).
// Weights staged permuted so the lane's 4 out-channel weights are one float4.
__global__ __launch_bounds__(256, 4) void denoise_fused(
    const float* __restrict__ x, const float* __restrict__ cw,
    const float* __restrict__ cb, float* __restrict__ out)
{
    __shared__ __align__(16) float xd[C_ * CW_];  // 16 KB: denoised chunk [c][64]
    __shared__ __align__(16) float Wt[C_ * C_];   // 16 KB: Wt[c*64+m*4+oi] = cw[(m+16*oi)*64+c]
    __shared__ float bnd[C_];                     // 256 B: vsum at px 63 per channel

    const int t    = threadIdx.x;
    const int b    = blockIdx.x >> 5;          // 32 batches
    const int h0   = (blockIdx.x & 31) * TH_;  // 32 strips of 4 rows
    const int lane = t & 63;
    const int wid  = t >> 6;                   // wave 0..3
    const int jj   = lane & 15;                // f4 index within chunk
    const int sub  = lane >> 4;                // 0..3
    const int m    = wid * 4 + sub;            // 0..15: lane's channel class

    // --- Stage Wt permuted+transposed via xd as swizzled scratch ---
    // A: coalesced global read, swizzled LDS write (conflict-free)
    for (int i = t; i < C_ * C_; i += 256) {
        int o = i >> 6, c = i & 63;
        xd[o * 64 + ((c + o) & 63)] = cw[i];
    }
    __syncthreads();
    // B: gather into permuted layout (banks: (c+o)%32, o bijective -> 2-way max)
    for (int k = t; k < C_ * C_; k += 256) {
        int c = k >> 6, r = k & 63;
        int o = (r >> 2) + ((r & 3) << 4);     // o = m + 16*oi
        Wt[k] = xd[o * 64 + ((c + o) & 63)];
    }
    __syncthreads();

    const float* xb = x   + (size_t)b * CHW_;
    float*       ob = out + (size_t)b * CHW_;

    float bias[4];
    #pragma unroll
    for (int oi = 0; oi < 4; ++oi) bias[oi] = cb[m + 16 * oi];

    for (int r = 0; r < TH_; ++r) {
        const int h = h0 + r;
        const bool hm = (h > 0), hp = (h < H_ - 1);
        const float rv = 1.f + (hm ? 1.f : 0.f) + (hp ? 1.f : 0.f);
        const float i3 = 1.f / (rv * 3.f);
        const float i2 = 1.f / (rv * 2.f);

        #pragma unroll
        for (int q = 0; q < 2; ++q) {
            float s[4][4];   // saved center x: residual for out-channel m+16p

            // ---- Filter chunk q: 4 passes x (4 waves x 4 sub) = 64 channels
            #pragma unroll
            for (int p = 0; p < 4; ++p) {
                const int c = 16 * p + m;
                const float* rc = xb + c * HW_ + h * W_ + q * CW_;
                float4 cen = ((const float4*)rc)[jj];
                s[p][0] = cen.x; s[p][1] = cen.y; s[p][2] = cen.z; s[p][3] = cen.w;
                float4 v = cen;
                if (hm) { float4 a = ((const float4*)(rc - W_))[jj]; v.x += a.x; v.y += a.y; v.z += a.z; v.w += a.w; }
                if (hp) { float4 a = ((const float4*)(rc + W_))[jj]; v.x += a.x; v.y += a.y; v.z += a.z; v.w += a.w; }
                // horizontal neighbors from adjacent lanes (16-group crossings
                // are exactly the jj==0 / jj==15 cases, which are masked)
                float L = __shfl_up(v.w, 1);
                float R = __shfl_down(v.x, 1);
                if (q == 0) {
                    if (jj == 15) {
                        bnd[c] = v.w;                 // stash vsum(px63) for F1
                        const float* rb = rc + CW_;   // px 64: recompute vsum
                        float vr = rb[0];
                        if (hm) vr += rb[-W_];
                        if (hp) vr += rb[W_];
                        R = vr;
                    }
                } else {
                    if (jj == 0) L = bnd[c];          // vsum(px63) from F0
                }
                float4 d;
                d.x = (q == 0 && jj == 0)  ? (v.x + v.y) * i2 : (L + v.x + v.y) * i3;
                d.y = (v.x + v.y + v.z) * i3;
                d.z = (v.y + v.z + v.w) * i3;
                d.w = (q == 1 && jj == 15) ? (v.z + v.w) * i2 : (v.z + v.w + R) * i3;
                ((float4*)xd)[c * 16 + jj] = d;
            }
            __syncthreads();

            // ---- 64x64 matmul: 4(o) x 4(px) per lane; residual+bias pre-folded
            float acc[4][4];
            #pragma unroll
            for (int oi = 0; oi < 4; ++oi) {
                acc[oi][0] = s[oi][0] + bias[oi];
                acc[oi][1] = s[oi][1] + bias[oi];
                acc[oi][2] = s[oi][2] + bias[oi];
                acc[oi][3] = s[oi][3] + bias[oi];
            }

            #pragma unroll 4
            for (int c = 0; c < C_; ++c) {
                float4 xv = ((const float4*)xd)[c * 16 + jj];     // bcast across sub
                float4 wv = *(const float4*)&Wt[c * 64 + m * 4];  // bcast across jj
                float w4[4] = { wv.x, wv.y, wv.z, wv.w };
                #pragma unroll
                for (int oi = 0; oi < 4; ++oi) {
                    acc[oi][0] += w4[oi] * xv.x;
                    acc[oi][1] += w4[oi] * xv.y;
                    acc[oi][2] += w4[oi] * xv.z;
                    acc[oi][3] += w4[oi] * xv.w;
                }
            }

            // ---- Store (no residual re-read: already folded in)
            #pragma unroll
            for (int oi = 0; oi < 4; ++oi) {
                float4 res;
                res.x = acc[oi][0]; res.y = acc[oi][1];
                res.z = acc[oi][2]; res.w = acc[oi][3];
                ((float4*)(ob + (m + 16 * oi) * HW_ + h * W_ + q * CW_))[jj] = res;
            }
            __syncthreads();   // protect xd + bnd before next chunk/row
        }
    }
}

extern "C" void kernel_launch(void* const* d_in, const int* in_sizes, int n_in,
                              void* d_out, int out_size, void* d_ws, size_t ws_size,
                              hipStream_t stream) {
    const float* x  = (const float*)d_in[0];
    const float* cw = (const float*)d_in[1];
    const float* cb = (const float*)d_in[2];
    float* out = (float*)d_out;
    dim3 grid(B_ * (H_ / TH_));   // 1024 blocks = exactly 4/CU co-resident
    dim3 block(256);
    hipLaunchKernelGGL(denoise_fused, grid, block, 0, stream, x, cw, cb, out);
}